// Round 11
// baseline (51.968 us; speedup 1.0000x reference)
//
#include <hip/hip_runtime.h>

// Fixed-shape problem
#define NBATCH 4
#define NPTS   8192
#define MTGT   8192
#define BN     (NBATCH*NPTS)      // 32768 sources (== total targets)
#define TPB    256
#define SPT    8                  // sources per thread (R2/R10-proven loop)
#define SPB    (TPB*SPT)          // 2048 sources per block (slice)
#define NXBLK  (BN/SPB)           // 16 slices (4 per batch)
#define CHUNK  128                // targets per chunk
#define NCHUNK (MTGT/CHUNK)       // 64 -> grid 16x64 = 1024 blocks (4/CU)

typedef float f32x2 __attribute__((ext_vector_type(2)));

__device__ __forceinline__ f32x2 pkfma(f32x2 a, f32x2 b, f32x2 c) {
    return __builtin_elementwise_fma(a, b, c);
}
__device__ __forceinline__ f32x2 pkmin(f32x2 a, f32x2 b) {
    return __builtin_elementwise_min(a, b);
}

// Pack targets once: pt[i] = (x, y, z, valid ? ||t||^2 : 1e30).
// Removes per-block staging AND the 16x-redundant tsq computation.
__global__ __launch_bounds__(256) void prep_kernel(const float* __restrict__ tgt,
                                                   float4* __restrict__ pt) {
    int i = blockIdx.x * 256 + threadIdx.x;    // 0..BN-1 (BN == NBATCH*MTGT)
    float x = tgt[(size_t)i * 3 + 0];
    float y = tgt[(size_t)i * 3 + 1];
    float z = tgt[(size_t)i * 3 + 2];
    float tsq = fmaf(x, x, fmaf(y, y, z * z));
    bool valid = (x != 0.f) || (y != 0.f) || (z != 0.f);
    pt[i] = make_float4(x, y, z, valid ? tsq : 1e30f);
}

// wspart layout: [slice][chunk][source-in-slice]; writer and reader coalesced;
// plain streaming stores, no atomics anywhere -> bit-deterministic.

// Per source point, min over one 128-target chunk of d' = ||t||^2 - 2 s.t.
// Targets come via WAVE-UNIFORM loads (s_load/K$ path) -- NO LDS, no syncthreads:
// the CU-shared LDS pipe (12cy per broadcast b128, 4 SIMDs competing) was the
// structural bottleneck of rounds 2-10.
__global__ __launch_bounds__(TPB, 4) void nn_min_kernel(const float* __restrict__ src,
                                                        const float4* __restrict__ pt,
                                                        float* __restrict__ wspart) {
    const int tid = threadIdx.x;
    const int bx  = blockIdx.x;          // 0..15 (source slice)
    const int c   = blockIdx.y;          // 0..63 (target chunk)
    const int b   = bx >> 2;             // 4 slices per batch

    const float4* __restrict__ tseg = pt + (size_t)b * MTGT + (size_t)c * CHUNK;

    // ---- 8 source points: 6 contiguous float4 = 96 B per thread ----
    const int s0 = bx * SPB + tid * SPT;
    const float4* sv = reinterpret_cast<const float4*>(src + (size_t)s0 * 3);
    float4 q0 = sv[0], q1 = sv[1], q2 = sv[2], q3 = sv[3], q4 = sv[4], q5 = sv[5];
    float sxs[8] = {q0.x, q0.w, q1.z, q2.y, q3.x, q3.w, q4.z, q5.y};
    float sys[8] = {q0.y, q1.x, q1.w, q2.z, q3.y, q4.x, q4.w, q5.z};
    float szs[8] = {q0.z, q1.y, q2.x, q2.w, q3.z, q4.y, q5.x, q5.w};

    f32x2 ax[4], ay[4], az[4], bmE[4], bmO[4];
#pragma unroll
    for (int p = 0; p < 4; ++p) {
        ax[p] = f32x2{-2.f * sxs[2 * p], -2.f * sxs[2 * p + 1]};
        ay[p] = f32x2{-2.f * sys[2 * p], -2.f * sys[2 * p + 1]};
        az[p] = f32x2{-2.f * szs[2 * p], -2.f * szs[2 * p + 1]};
        bmE[p] = f32x2{3e38f, 3e38f};
        bmO[p] = f32x2{3e38f, 3e38f};
    }

    // ---- inner loop (R10 body, load path changed LDS -> uniform global):
    //      2 uniform 16B loads feed 64 VALU instructions ----
#pragma unroll 2
    for (int m = 0; m < CHUNK; m += 2) {
        float4 t0 = tseg[m], t1 = tseg[m + 1];
        f32x2 t0x = {t0.x, t0.x}, t0y = {t0.y, t0.y}, t0z = {t0.z, t0.z}, t0w = {t0.w, t0.w};
        f32x2 t1x = {t1.x, t1.x}, t1y = {t1.y, t1.y}, t1z = {t1.z, t1.z}, t1w = {t1.w, t1.w};
#pragma unroll
        for (int p = 0; p < 4; ++p) {
            bmE[p] = pkmin(bmE[p], pkfma(ax[p], t0x, pkfma(ay[p], t0y, pkfma(az[p], t0z, t0w))));
            bmO[p] = pkmin(bmO[p], pkfma(ax[p], t1x, pkfma(ay[p], t1y, pkfma(az[p], t1z, t1w))));
        }
    }

    f32x2 r0 = pkmin(bmE[0], bmO[0]);
    f32x2 r1 = pkmin(bmE[1], bmO[1]);
    f32x2 r2 = pkmin(bmE[2], bmO[2]);
    f32x2 r3 = pkmin(bmE[3], bmO[3]);

    // ---- two coalesced 16B streaming stores per thread ----
    float4* wp = reinterpret_cast<float4*>(
        wspart + ((size_t)bx * NCHUNK + c) * SPB) + tid * 2;
    wp[0] = make_float4(r0.x, r0.y, r1.x, r1.y);
    wp[1] = make_float4(r2.x, r2.y, r3.x, r3.y);
}

// 128 blocks: (slice, k-of-8). Min over 64 chunk-partials (coalesced: for
// fixed (k,c) a wave reads 1 KB consecutive), then deterministic partials.
__global__ __launch_bounds__(256) void reduce_kernel(const float* __restrict__ src,
                                                     const float* __restrict__ wspart,
                                                     double* __restrict__ partials) {
    const int blk   = blockIdx.x;        // 0..127
    const int slice = blk >> 3, k = blk & 7;
    const int tid   = threadIdx.x;
    const float* wp = wspart + (size_t)slice * NCHUNK * SPB;

    const int s   = k * 256 + tid;       // source within slice
    const int gid = slice * SPB + s;

    float m = 3e38f;
#pragma unroll 4
    for (int c = 0; c < NCHUNK; ++c) m = fminf(m, wp[(size_t)c * SPB + s]);

    float sx = src[(size_t)gid * 3 + 0];
    float sy = src[(size_t)gid * 3 + 1];
    float sz = src[(size_t)gid * 3 + 2];
    bool valid = (sx != 0.f) || (sy != 0.f) || (sz != 0.f);
    float ssq = fmaf(sx, sx, fmaf(sy, sy, sz * sz));
    float sq = fmaxf(0.f, ssq + m);

    __shared__ double sh[512];
    sh[tid] = valid ? (double)sq : 0.0;
    sh[256 + tid] = valid ? 1.0 : 0.0;
    __syncthreads();
    for (int t = 128; t > 0; t >>= 1) {
        if (tid < t) { sh[tid] += sh[tid + t]; sh[256 + tid] += sh[256 + tid + t]; }
        __syncthreads();
    }
    if (tid == 0) { partials[2 * blk] = sh[0]; partials[2 * blk + 1] = sh[256]; }
}

// Fixed-order final combine: bit-deterministic scalar output.
// Batch t owns slices 4t..4t+3 -> partial blocks 32t..32t+31.
__global__ void final_kernel(const double* __restrict__ partials, float* __restrict__ out) {
    __shared__ double bmv[4];
    int t = threadIdx.x;
    if (t < 4) {
        double s = 0.0, c = 0.0;
        for (int i = 0; i < 32; ++i) {
            s += partials[2 * (t * 32 + i)];
            c += partials[2 * (t * 32 + i) + 1];
        }
        if (c < 1.0) c = 1.0;
        bmv[t] = s / (3.0 * c);
    }
    __syncthreads();
    if (t == 0) out[0] = (float)((bmv[0] + bmv[1] + bmv[2] + bmv[3]) * 0.25);
}

extern "C" void kernel_launch(void* const* d_in, const int* in_sizes, int n_in,
                              void* d_out, int out_size, void* d_ws, size_t ws_size,
                              hipStream_t stream) {
    const float* src = (const float*)d_in[0];
    const float* tgt = (const float*)d_in[1];
    float* out = (float*)d_out;

    float4* pt       = (float4*)d_ws;                                  // 512 KiB
    float*  wspart   = (float*)((char*)d_ws + (size_t)BN * 16);        // 8 MiB
    double* partials = (double*)((char*)d_ws + (size_t)BN * 16 +
                                 (size_t)NXBLK * NCHUNK * SPB * sizeof(float)); // 2 KiB

    prep_kernel<<<dim3(BN / 256), dim3(256), 0, stream>>>(tgt, pt);
    nn_min_kernel<<<dim3(NXBLK, NCHUNK), dim3(TPB), 0, stream>>>(src, pt, wspart);
    reduce_kernel<<<dim3(NXBLK * 8), dim3(256), 0, stream>>>(src, wspart, partials);
    final_kernel<<<dim3(1), dim3(64), 0, stream>>>(partials, out);
}

// Round 12
// 44.343 us; speedup vs baseline: 1.1720x; 1.1720x over previous
//
#include <hip/hip_runtime.h>

// Fixed-shape problem
#define NBATCH 4
#define NPTS   8192
#define MTGT   8192
#define BN     (NBATCH*NPTS)      // 32768 sources
#define TPB    128
#define SPT    16                 // sources per thread (named scalars, no arrays)
#define SPB    (TPB*SPT)          // 2048 sources per block (slice)
#define NXBLK  (BN/SPB)           // 16 slices (4 per batch)
#define CHUNK  128                // targets staged per block
#define NCHUNK (MTGT/CHUNK)       // 64 -> grid 16x64 = 1024 blocks (8 blocks/CU)

// --- macro machinery: 16 sources as named scalars (NO arrays -> NO scratch) ---
#define FOR16(X) X(0) X(1) X(2) X(3) X(4) X(5) X(6) X(7) \
                 X(8) X(9) X(10) X(11) X(12) X(13) X(14) X(15)

#define DECL_S(i) float ax##i, ay##i, az##i, bm##i = 3e38f;

// group g: sources 4g..4g+3 live in float4 sv[3g..3g+2]
#define LOAD_G(g, A, B, C, D)                                         \
    {   float4 qa = sv[3*(g)], qb = sv[3*(g)+1], qc = sv[3*(g)+2];    \
        ax##A = -2.f*qa.x; ay##A = -2.f*qa.y; az##A = -2.f*qa.z;      \
        ax##B = -2.f*qa.w; ay##B = -2.f*qb.x; az##B = -2.f*qb.y;      \
        ax##C = -2.f*qb.z; ay##C = -2.f*qb.w; az##C = -2.f*qc.x;      \
        ax##D = -2.f*qc.y; ay##D = -2.f*qc.z; az##D = -2.f*qc.w; }

#define BODY(i)                                                                   \
    {   float d0 = fmaf(ax##i, t0.x, fmaf(ay##i, t0.y, fmaf(az##i, t0.z, t0.w))); \
        float d1 = fmaf(ax##i, t1.x, fmaf(ay##i, t1.y, fmaf(az##i, t1.z, t1.w))); \
        bm##i = fminf(bm##i, fminf(d0, d1)); }

// wspart layout: [slice][chunk][source-in-slice]; writer and reader coalesced;
// plain streaming stores, no atomics anywhere -> bit-deterministic.

// Per source point, min over one 128-target chunk of d' = ||t||^2 - 2 s.t
// (exact sq distance = d' + ||s||^2, added in reduce).
// __launch_bounds__(128, 2): VGPR cap 256 -> ~95 live scalars fit, NO spill.
// (Default heuristic capped SPT=16 at 52 VGPRs in round 8 -> spill disaster.)
__global__ __launch_bounds__(TPB, 2) void nn_min_kernel(const float* __restrict__ src,
                                                        const float* __restrict__ tgt,
                                                        float* __restrict__ wspart) {
    __shared__ float  raw[CHUNK * 3];   // 1.5 KiB
    __shared__ float4 lt[CHUNK];        // 2 KiB: (x,y,z,||t||^2); invalid -> 1e30

    const int tid = threadIdx.x;
    const int bx  = blockIdx.x;          // 0..15 (source slice)
    const int c   = blockIdx.y;          // 0..63 (target chunk)
    const int b   = bx >> 2;             // 4 slices per batch

    // ---- stage CHUNK targets (coalesced float4; 96 of 128 threads) ----
    const float4* tv = reinterpret_cast<const float4*>(
        tgt + ((size_t)b * MTGT + (size_t)c * CHUNK) * 3);
    if (tid < CHUNK * 3 / 4) reinterpret_cast<float4*>(raw)[tid] = tv[tid];
    __syncthreads();
    {
        float x = raw[3 * tid], y = raw[3 * tid + 1], z = raw[3 * tid + 2];
        float tsq = fmaf(x, x, fmaf(y, y, z * z));
        bool valid = (x != 0.f) || (y != 0.f) || (z != 0.f);
        lt[tid] = make_float4(x, y, z, valid ? tsq : 1e30f);
    }
    __syncthreads();

    // ---- 16 source points: 12 contiguous float4 = 192 B per thread ----
    const int s0 = bx * SPB + tid * SPT;
    const float4* sv = reinterpret_cast<const float4*>(src + (size_t)s0 * 3);

    FOR16(DECL_S)
    LOAD_G(0,  0,  1,  2,  3)
    LOAD_G(1,  4,  5,  6,  7)
    LOAD_G(2,  8,  9, 10, 11)
    LOAD_G(3, 12, 13, 14, 15)

    // ---- inner loop: 2 broadcast ds_read_b128 feed 112 VALU instructions
    //      (LDS pipe ~43% busy at 16 waves/CU -> VALU-bound by construction) ----
#pragma unroll 2
    for (int m = 0; m < CHUNK; m += 2) {
        float4 t0 = lt[m], t1 = lt[m + 1];
        FOR16(BODY)
    }

    // ---- four coalesced 16B streaming stores per thread ----
    float4* wp = reinterpret_cast<float4*>(
        wspart + ((size_t)bx * NCHUNK + c) * SPB) + tid * 4;
    wp[0] = make_float4(bm0,  bm1,  bm2,  bm3);
    wp[1] = make_float4(bm4,  bm5,  bm6,  bm7);
    wp[2] = make_float4(bm8,  bm9,  bm10, bm11);
    wp[3] = make_float4(bm12, bm13, bm14, bm15);
}

// 128 blocks: (slice, k-of-8). Min over 64 chunk-partials (coalesced: for
// fixed (k,c) a wave reads 1 KB consecutive), then deterministic partials.
__global__ __launch_bounds__(256) void reduce_kernel(const float* __restrict__ src,
                                                     const float* __restrict__ wspart,
                                                     double* __restrict__ partials) {
    const int blk   = blockIdx.x;        // 0..127
    const int slice = blk >> 3, k = blk & 7;
    const int tid   = threadIdx.x;
    const float* wp = wspart + (size_t)slice * NCHUNK * SPB;

    const int s   = k * 256 + tid;       // source within slice (0..2047)
    const int gid = slice * SPB + s;

    float m = 3e38f;
#pragma unroll 4
    for (int c = 0; c < NCHUNK; ++c) m = fminf(m, wp[(size_t)c * SPB + s]);

    float sx = src[(size_t)gid * 3 + 0];
    float sy = src[(size_t)gid * 3 + 1];
    float sz = src[(size_t)gid * 3 + 2];
    bool valid = (sx != 0.f) || (sy != 0.f) || (sz != 0.f);
    float ssq = fmaf(sx, sx, fmaf(sy, sy, sz * sz));
    float sq = fmaxf(0.f, ssq + m);

    __shared__ double sh[512];
    sh[tid] = valid ? (double)sq : 0.0;
    sh[256 + tid] = valid ? 1.0 : 0.0;
    __syncthreads();
    for (int t = 128; t > 0; t >>= 1) {
        if (tid < t) { sh[tid] += sh[tid + t]; sh[256 + tid] += sh[256 + tid + t]; }
        __syncthreads();
    }
    if (tid == 0) { partials[2 * blk] = sh[0]; partials[2 * blk + 1] = sh[256]; }
}

// Fixed-order final combine: bit-deterministic scalar output.
// Batch t owns slices 4t..4t+3 -> partial blocks 32t..32t+31.
__global__ void final_kernel(const double* __restrict__ partials, float* __restrict__ out) {
    __shared__ double bmv[4];
    int t = threadIdx.x;
    if (t < 4) {
        double s = 0.0, c = 0.0;
        for (int i = 0; i < 32; ++i) {
            s += partials[2 * (t * 32 + i)];
            c += partials[2 * (t * 32 + i) + 1];
        }
        if (c < 1.0) c = 1.0;
        bmv[t] = s / (3.0 * c);
    }
    __syncthreads();
    if (t == 0) out[0] = (float)((bmv[0] + bmv[1] + bmv[2] + bmv[3]) * 0.25);
}

extern "C" void kernel_launch(void* const* d_in, const int* in_sizes, int n_in,
                              void* d_out, int out_size, void* d_ws, size_t ws_size,
                              hipStream_t stream) {
    const float* src = (const float*)d_in[0];
    const float* tgt = (const float*)d_in[1];
    float* out = (float*)d_out;

    float*  wspart   = (float*)d_ws;                                  // 8 MiB
    double* partials = (double*)((char*)d_ws +
                                 (size_t)NXBLK * NCHUNK * SPB * sizeof(float)); // 2 KiB

    nn_min_kernel<<<dim3(NXBLK, NCHUNK), dim3(TPB), 0, stream>>>(src, tgt, wspart);
    reduce_kernel<<<dim3(NXBLK * 8), dim3(256), 0, stream>>>(src, wspart, partials);
    final_kernel<<<dim3(1), dim3(64), 0, stream>>>(partials, out);
}

// Round 13
// 29.464 us; speedup vs baseline: 1.7638x; 1.5050x over previous
//
#include <hip/hip_runtime.h>

// Fixed-shape problem
#define NBATCH 4
#define NPTS   8192
#define MTGT   8192
#define BN     (NBATCH*NPTS)      // 32768 sources (== total targets)
#define NCHUNK 8                  // target chunks per batch (1024 targets each)
#define SGRP   32                 // source groups per batch (256 sources each)
// grid: (32, 8, 4) = 1024 blocks of 256 threads (4 waves); wave = 64 sources x 1024 targets

typedef __attribute__((ext_vector_type(8)))  short bf16x8;   // guide-verified frag type
typedef __attribute__((ext_vector_type(16))) float f32x16;

__device__ __forceinline__ unsigned short f2bf(float x) {   // RNE fp32->bf16
    unsigned u = __float_as_uint(x);
    return (unsigned short)((u + 0x7fffu + ((u >> 16) & 1u)) >> 16);
}
__device__ __forceinline__ float bf2f(unsigned short h) {
    return __uint_as_float(((unsigned)h) << 16);
}

// Pack A (sources, scaled by -2, hi/lo split) and B (targets hi/lo + ||t||^2
// 3-way split) into MFMA fragment order. Slot pairing (A-elem x B-elem):
//   h=0 e0-2: -2s_hi * t_hi   h=0 e3-5: -2s_lo * t_hi
//   h=0 e6-7 + h=1 e0: -2s_hi * t_lo
//   h=1 e1-3: 1.0 * tsq_{h,m,l}     rest: 0
// => D = tsq - 2*s.t (+eps ~5e-5). Dot is invariant to any k-permutation
// common to A and B, so only row/col = lane&31 and the VERIFIED C/D map matter.
__global__ __launch_bounds__(256) void prep_kernel(const float* __restrict__ src,
                                                   const float* __restrict__ tgt,
                                                   unsigned short* __restrict__ Apk,
                                                   unsigned short* __restrict__ Bpk) {
    const int i = blockIdx.x * 256 + threadIdx.x;   // 0..BN-1
    const int T = i >> 5, l = i & 31;
    const unsigned ONE = 0x3F80u;

    // ---- A: a = -2*s
    float sx = src[3*(size_t)i], sy = src[3*(size_t)i+1], sz = src[3*(size_t)i+2];
    float axf = -2.f*sx, ayf = -2.f*sy, azf = -2.f*sz;
    unsigned axh = f2bf(axf), ayh = f2bf(ayf), azh = f2bf(azf);
    unsigned axl = f2bf(axf - bf2f(axh));
    unsigned ayl = f2bf(ayf - bf2f(ayh));
    unsigned azl = f2bf(azf - bf2f(azh));
    uint4* a0 = (uint4*)(Apk + ((size_t)T*64 +      l) * 8);
    uint4* a1 = (uint4*)(Apk + ((size_t)T*64 + 32 + l) * 8);
    *a0 = make_uint4(axh | (ayh<<16), azh | (axl<<16), ayl | (azl<<16), axh | (ayh<<16));
    *a1 = make_uint4(azh | (ONE<<16), ONE | (ONE<<16), 0u, 0u);

    // ---- B: t hi/lo + tsq 3-split (invalid target -> tsq = 1e30)
    float tx = tgt[3*(size_t)i], ty = tgt[3*(size_t)i+1], tz = tgt[3*(size_t)i+2];
    unsigned txh = f2bf(tx), tyh = f2bf(ty), tzh = f2bf(tz);
    unsigned txl = f2bf(tx - bf2f(txh));
    unsigned tyl = f2bf(ty - bf2f(tyh));
    unsigned tzl = f2bf(tz - bf2f(tzh));
    float tsq = fmaf(tx, tx, fmaf(ty, ty, tz * tz));
    bool valid = (tx != 0.f) || (ty != 0.f) || (tz != 0.f);
    unsigned qh, qm, ql;
    if (valid) {
        qh = f2bf(tsq);
        float r1 = tsq - bf2f(qh); qm = f2bf(r1);
        float r2 = r1 - bf2f(qm);  ql = f2bf(r2);
    } else { qh = f2bf(1e30f); qm = 0u; ql = 0u; }
    uint4* b0 = (uint4*)(Bpk + ((size_t)T*64 +      l) * 8);
    uint4* b1 = (uint4*)(Bpk + ((size_t)T*64 + 32 + l) * 8);
    *b0 = make_uint4(txh | (tyh<<16), tzh | (txh<<16), tyh | (tzh<<16), txl | (tyl<<16));
    *b1 = make_uint4(tzl | (qh<<16), qm | (ql<<16), 0u, 0u);
}

// Per wave: 2 source strips (2x32 rows) x 32 target tiles (32 cols each).
// D[i,j] = tsq[j] - 2 s_i.t_j via one MFMA per (strip, tile); running
// elementwise min in registers; cross-lane min + coalesced float4 stores.
__global__ __launch_bounds__(256, 4) void nn_mfma_kernel(const unsigned short* __restrict__ Apk,
                                                         const unsigned short* __restrict__ Bpk,
                                                         float* __restrict__ wspart) {
    const int lane = threadIdx.x & 63, wid = threadIdx.x >> 6;
    const int sg = blockIdx.x, cy = blockIdx.y, bz = blockIdx.z;

    const bf16x8* Ap = (const bf16x8*)Apk;
    const bf16x8* Bp = (const bf16x8*)Bpk;

    const int Ts0 = bz * 256 + sg * 8 + wid * 2;      // source tile (32 rows) base
    bf16x8 a0 = Ap[(size_t)Ts0 * 64 + lane];
    bf16x8 a1 = Ap[(size_t)(Ts0 + 1) * 64 + lane];

    f32x16 z, bm0, bm1;
#pragma unroll
    for (int e = 0; e < 16; ++e) { z[e] = 0.f; bm0[e] = 3e38f; bm1[e] = 3e38f; }

    const int Tb0 = bz * 256 + cy * 32;               // target tile base for chunk
    const bf16x8* bp = Bp + (size_t)Tb0 * 64 + lane;

#pragma unroll 2
    for (int m = 0; m < 32; ++m) {
        bf16x8 bf = bp[(size_t)m * 64];               // 16B/lane coalesced; L1-shared by 4 waves
        f32x16 d0 = __builtin_amdgcn_mfma_f32_32x32x16_bf16(a0, bf, z, 0, 0, 0);
        f32x16 d1 = __builtin_amdgcn_mfma_f32_32x32x16_bf16(a1, bf, z, 0, 0, 0);
        bm0 = __builtin_elementwise_min(bm0, d0);
        bm1 = __builtin_elementwise_min(bm1, d1);
    }

    // cross-lane min over the 32 cols (xor masks <32 stay within each half)
#pragma unroll
    for (int e = 0; e < 16; ++e) {
        float v0 = bm0[e], v1 = bm1[e];
#pragma unroll
        for (int off = 16; off > 0; off >>= 1) {
            v0 = fminf(v0, __shfl_xor(v0, off));
            v1 = fminf(v1, __shfl_xor(v1, off));
        }
        bm0[e] = v0; bm1[e] = v1;
    }

    // writer lanes 0 (h=0) and 32 (h=1). C/D map (m74/m101 verified):
    // row = (reg&3) + 8*(reg>>2) + 4*(lane>>5)  -> reg 4q+e covers rows 8q+4h+e
    if ((lane & 31) == 0) {
        const int h = lane >> 5;
        float* wb = wspart + (size_t)cy * BN + (size_t)bz * NPTS + sg * 256 + wid * 64 + 4 * h;
#pragma unroll
        for (int q = 0; q < 4; ++q) {
            *(float4*)(wb + 8 * q)      = make_float4(bm0[4*q], bm0[4*q+1], bm0[4*q+2], bm0[4*q+3]);
            *(float4*)(wb + 8 * q + 32) = make_float4(bm1[4*q], bm1[4*q+1], bm1[4*q+2], bm1[4*q+3]);
        }
    }
}

// 128 blocks x 256: min over 8 chunk-partials (coalesced), + ||s||^2, validity,
// fixed-order double partials -> bit-deterministic.
__global__ __launch_bounds__(256) void reduce_kernel(const float* __restrict__ src,
                                                     const float* __restrict__ wspart,
                                                     double* __restrict__ partials) {
    const int blk = blockIdx.x, tid = threadIdx.x;
    const int gid = blk * 256 + tid;

    float m = 3e38f;
#pragma unroll
    for (int c = 0; c < NCHUNK; ++c) m = fminf(m, wspart[(size_t)c * BN + gid]);

    float sx = src[3*(size_t)gid], sy = src[3*(size_t)gid+1], sz = src[3*(size_t)gid+2];
    bool valid = (sx != 0.f) || (sy != 0.f) || (sz != 0.f);
    float ssq = fmaf(sx, sx, fmaf(sy, sy, sz * sz));
    float sq = fmaxf(0.f, ssq + m);

    __shared__ double sh[512];
    sh[tid] = valid ? (double)sq : 0.0;
    sh[256 + tid] = valid ? 1.0 : 0.0;
    __syncthreads();
    for (int s = 128; s > 0; s >>= 1) {
        if (tid < s) { sh[tid] += sh[tid + s]; sh[256 + tid] += sh[256 + tid + s]; }
        __syncthreads();
    }
    if (tid == 0) { partials[2 * blk] = sh[0]; partials[2 * blk + 1] = sh[256]; }
}

// Fixed-order final combine (batch t owns partial blocks 32t..32t+31).
__global__ void final_kernel(const double* __restrict__ partials, float* __restrict__ out) {
    __shared__ double bmv[4];
    int t = threadIdx.x;
    if (t < 4) {
        double s = 0.0, c = 0.0;
        for (int i = 0; i < 32; ++i) {
            s += partials[2 * (t * 32 + i)];
            c += partials[2 * (t * 32 + i) + 1];
        }
        if (c < 1.0) c = 1.0;
        bmv[t] = s / (3.0 * c);
    }
    __syncthreads();
    if (t == 0) out[0] = (float)((bmv[0] + bmv[1] + bmv[2] + bmv[3]) * 0.25);
}

extern "C" void kernel_launch(void* const* d_in, const int* in_sizes, int n_in,
                              void* d_out, int out_size, void* d_ws, size_t ws_size,
                              hipStream_t stream) {
    const float* src = (const float*)d_in[0];
    const float* tgt = (const float*)d_in[1];
    float* out = (float*)d_out;

    // ws: Apk 1MB | Bpk 1MB | wspart 1MB | partials 2KB
    unsigned short* Apk = (unsigned short*)d_ws;
    unsigned short* Bpk = (unsigned short*)((char*)d_ws + (1u << 20));
    float* wspart       = (float*)((char*)d_ws + (2u << 20));
    double* partials    = (double*)((char*)d_ws + (3u << 20));

    prep_kernel<<<dim3(BN / 256), dim3(256), 0, stream>>>(src, tgt, Apk, Bpk);
    nn_mfma_kernel<<<dim3(SGRP, NCHUNK, NBATCH), dim3(256), 0, stream>>>(Apk, Bpk, wspart);
    reduce_kernel<<<dim3(BN / 256), dim3(256), 0, stream>>>(src, wspart, partials);
    final_kernel<<<dim3(1), dim3(64), 0, stream>>>(partials, out);
}

// Round 14
// 28.678 us; speedup vs baseline: 1.8121x; 1.0274x over previous
//
#include <hip/hip_runtime.h>

// Fixed-shape problem
#define NBATCH 4
#define NPTS   8192
#define MTGT   8192
#define BN     (NBATCH*NPTS)      // 32768 sources (== total targets)
#define NCHUNK 8                  // target chunks per batch (1024 targets each)
#define SGRP   32                 // source groups per batch (256 sources each)
// grid: (32, 8, 4) = 1024 blocks of 256 threads (4 waves); wave = 64 sources x 1024 targets

typedef __attribute__((ext_vector_type(8)))  short bf16x8;   // guide-verified frag type
typedef __attribute__((ext_vector_type(16))) float f32x16;

__device__ __forceinline__ unsigned short f2bf(float x) {   // RNE fp32->bf16
    unsigned u = __float_as_uint(x);
    return (unsigned short)((u + 0x7fffu + ((u >> 16) & 1u)) >> 16);
}
__device__ __forceinline__ float bf2f(unsigned short h) {
    return __uint_as_float(((unsigned)h) << 16);
}

// Pack A (sources, scaled by -2, hi/lo split) and B (targets hi/lo + ||t||^2
// 3-way split) into MFMA fragment order. Slot pairing (A-elem x B-elem):
//   h=0 e0-2: -2s_hi * t_hi   h=0 e3-5: -2s_lo * t_hi
//   h=0 e6-7 + h=1 e0: -2s_hi * t_lo
//   h=1 e1-3: 1.0 * tsq_{h,m,l}     rest: 0
// => D = tsq - 2*s.t (+eps ~5e-5). Dot is invariant to any k-permutation
// common to A and B, so only row/col = lane&31 and the VERIFIED C/D map matter.
__global__ __launch_bounds__(256) void prep_kernel(const float* __restrict__ src,
                                                   const float* __restrict__ tgt,
                                                   unsigned short* __restrict__ Apk,
                                                   unsigned short* __restrict__ Bpk) {
    const int i = blockIdx.x * 256 + threadIdx.x;   // 0..BN-1
    const int T = i >> 5, l = i & 31;
    const unsigned ONE = 0x3F80u;

    // ---- A: a = -2*s
    float sx = src[3*(size_t)i], sy = src[3*(size_t)i+1], sz = src[3*(size_t)i+2];
    float axf = -2.f*sx, ayf = -2.f*sy, azf = -2.f*sz;
    unsigned axh = f2bf(axf), ayh = f2bf(ayf), azh = f2bf(azf);
    unsigned axl = f2bf(axf - bf2f(axh));
    unsigned ayl = f2bf(ayf - bf2f(ayh));
    unsigned azl = f2bf(azf - bf2f(azh));
    uint4* a0 = (uint4*)(Apk + ((size_t)T*64 +      l) * 8);
    uint4* a1 = (uint4*)(Apk + ((size_t)T*64 + 32 + l) * 8);
    *a0 = make_uint4(axh | (ayh<<16), azh | (axl<<16), ayl | (azl<<16), axh | (ayh<<16));
    *a1 = make_uint4(azh | (ONE<<16), ONE | (ONE<<16), 0u, 0u);

    // ---- B: t hi/lo + tsq 3-split (invalid target -> tsq = 1e30)
    float tx = tgt[3*(size_t)i], ty = tgt[3*(size_t)i+1], tz = tgt[3*(size_t)i+2];
    unsigned txh = f2bf(tx), tyh = f2bf(ty), tzh = f2bf(tz);
    unsigned txl = f2bf(tx - bf2f(txh));
    unsigned tyl = f2bf(ty - bf2f(tyh));
    unsigned tzl = f2bf(tz - bf2f(tzh));
    float tsq = fmaf(tx, tx, fmaf(ty, ty, tz * tz));
    bool valid = (tx != 0.f) || (ty != 0.f) || (tz != 0.f);
    unsigned qh, qm, ql;
    if (valid) {
        qh = f2bf(tsq);
        float r1 = tsq - bf2f(qh); qm = f2bf(r1);
        float r2 = r1 - bf2f(qm);  ql = f2bf(r2);
    } else { qh = f2bf(1e30f); qm = 0u; ql = 0u; }
    uint4* b0 = (uint4*)(Bpk + ((size_t)T*64 +      l) * 8);
    uint4* b1 = (uint4*)(Bpk + ((size_t)T*64 + 32 + l) * 8);
    *b0 = make_uint4(txh | (tyh<<16), tzh | (txh<<16), tyh | (tzh<<16), txl | (tyl<<16));
    *b1 = make_uint4(tzl | (qh<<16), qm | (ql<<16), 0u, 0u);
}

// Per wave: 2 source strips (2x32 rows) x 32 target tiles (32 cols each).
// 4 independent MFMAs per iteration; running min uses v_min3-fusable
// fminf(fminf(dA,dB), bm) -> HALF the VALU of the round-13 loop.
__global__ __launch_bounds__(256, 4) void nn_mfma_kernel(const unsigned short* __restrict__ Apk,
                                                         const unsigned short* __restrict__ Bpk,
                                                         float* __restrict__ wspart) {
    const int lane = threadIdx.x & 63, wid = threadIdx.x >> 6;
    const int sg = blockIdx.x, cy = blockIdx.y, bz = blockIdx.z;

    const bf16x8* Ap = (const bf16x8*)Apk;
    const bf16x8* Bp = (const bf16x8*)Bpk;

    const int Ts0 = bz * 256 + sg * 8 + wid * 2;      // source tile (32 rows) base
    bf16x8 a0 = Ap[(size_t)Ts0 * 64 + lane];
    bf16x8 a1 = Ap[(size_t)(Ts0 + 1) * 64 + lane];

    f32x16 z, bm0, bm1;
#pragma unroll
    for (int e = 0; e < 16; ++e) { z[e] = 0.f; bm0[e] = 3e38f; bm1[e] = 3e38f; }

    const int Tb0 = bz * 256 + cy * 32;               // target tile base for chunk
    const bf16x8* bp = Bp + (size_t)Tb0 * 64 + lane;

#pragma unroll 2
    for (int m = 0; m < 32; m += 2) {
        bf16x8 bfA = bp[(size_t)m * 64];              // 16B/lane coalesced; L1-shared
        bf16x8 bfB = bp[(size_t)(m + 1) * 64];
        f32x16 d0A = __builtin_amdgcn_mfma_f32_32x32x16_bf16(a0, bfA, z, 0, 0, 0);
        f32x16 d0B = __builtin_amdgcn_mfma_f32_32x32x16_bf16(a0, bfB, z, 0, 0, 0);
        f32x16 d1A = __builtin_amdgcn_mfma_f32_32x32x16_bf16(a1, bfA, z, 0, 0, 0);
        f32x16 d1B = __builtin_amdgcn_mfma_f32_32x32x16_bf16(a1, bfB, z, 0, 0, 0);
#pragma unroll
        for (int e = 0; e < 16; ++e) {
            bm0[e] = fminf(fminf(d0A[e], d0B[e]), bm0[e]);   // -> v_min3_f32
            bm1[e] = fminf(fminf(d1A[e], d1B[e]), bm1[e]);
        }
    }

    // cross-lane min over the 32 cols (xor masks <32 stay within each half)
#pragma unroll
    for (int e = 0; e < 16; ++e) {
        float v0 = bm0[e], v1 = bm1[e];
#pragma unroll
        for (int off = 16; off > 0; off >>= 1) {
            v0 = fminf(v0, __shfl_xor(v0, off));
            v1 = fminf(v1, __shfl_xor(v1, off));
        }
        bm0[e] = v0; bm1[e] = v1;
    }

    // writer lanes 0 (h=0) and 32 (h=1). C/D map (m74/m101 verified):
    // row = (reg&3) + 8*(reg>>2) + 4*(lane>>5)  -> reg 4q+e covers rows 8q+4h+e
    if ((lane & 31) == 0) {
        const int h = lane >> 5;
        float* wb = wspart + (size_t)cy * BN + (size_t)bz * NPTS + sg * 256 + wid * 64 + 4 * h;
#pragma unroll
        for (int q = 0; q < 4; ++q) {
            *(float4*)(wb + 8 * q)      = make_float4(bm0[4*q], bm0[4*q+1], bm0[4*q+2], bm0[4*q+3]);
            *(float4*)(wb + 8 * q + 32) = make_float4(bm1[4*q], bm1[4*q+1], bm1[4*q+2], bm1[4*q+3]);
        }
    }
}

// 128 blocks x 256: min over 8 chunk-partials (coalesced), + ||s||^2, validity,
// fixed-order double partials -> bit-deterministic.
__global__ __launch_bounds__(256) void reduce_kernel(const float* __restrict__ src,
                                                     const float* __restrict__ wspart,
                                                     double* __restrict__ partials) {
    const int blk = blockIdx.x, tid = threadIdx.x;
    const int gid = blk * 256 + tid;

    float m = 3e38f;
#pragma unroll
    for (int c = 0; c < NCHUNK; ++c) m = fminf(m, wspart[(size_t)c * BN + gid]);

    float sx = src[3*(size_t)gid], sy = src[3*(size_t)gid+1], sz = src[3*(size_t)gid+2];
    bool valid = (sx != 0.f) || (sy != 0.f) || (sz != 0.f);
    float ssq = fmaf(sx, sx, fmaf(sy, sy, sz * sz));
    float sq = fmaxf(0.f, ssq + m);

    __shared__ double sh[512];
    sh[tid] = valid ? (double)sq : 0.0;
    sh[256 + tid] = valid ? 1.0 : 0.0;
    __syncthreads();
    for (int s = 128; s > 0; s >>= 1) {
        if (tid < s) { sh[tid] += sh[tid + s]; sh[256 + tid] += sh[256 + tid + s]; }
        __syncthreads();
    }
    if (tid == 0) { partials[2 * blk] = sh[0]; partials[2 * blk + 1] = sh[256]; }
}

// Fixed-order final combine (batch t owns partial blocks 32t..32t+31).
__global__ void final_kernel(const double* __restrict__ partials, float* __restrict__ out) {
    __shared__ double bmv[4];
    int t = threadIdx.x;
    if (t < 4) {
        double s = 0.0, c = 0.0;
        for (int i = 0; i < 32; ++i) {
            s += partials[2 * (t * 32 + i)];
            c += partials[2 * (t * 32 + i) + 1];
        }
        if (c < 1.0) c = 1.0;
        bmv[t] = s / (3.0 * c);
    }
    __syncthreads();
    if (t == 0) out[0] = (float)((bmv[0] + bmv[1] + bmv[2] + bmv[3]) * 0.25);
}

extern "C" void kernel_launch(void* const* d_in, const int* in_sizes, int n_in,
                              void* d_out, int out_size, void* d_ws, size_t ws_size,
                              hipStream_t stream) {
    const float* src = (const float*)d_in[0];
    const float* tgt = (const float*)d_in[1];
    float* out = (float*)d_out;

    // ws: Apk 1MB | Bpk 1MB | wspart 1MB | partials 2KB
    unsigned short* Apk = (unsigned short*)d_ws;
    unsigned short* Bpk = (unsigned short*)((char*)d_ws + (1u << 20));
    float* wspart       = (float*)((char*)d_ws + (2u << 20));
    double* partials    = (double*)((char*)d_ws + (3u << 20));

    prep_kernel<<<dim3(BN / 256), dim3(256), 0, stream>>>(src, tgt, Apk, Bpk);
    nn_mfma_kernel<<<dim3(SGRP, NCHUNK, NBATCH), dim3(256), 0, stream>>>(Apk, Bpk, wspart);
    reduce_kernel<<<dim3(BN / 256), dim3(256), 0, stream>>>(src, wspart, partials);
    final_kernel<<<dim3(1), dim3(64), 0, stream>>>(partials, out);
}